// Round 9
// baseline (324.377 us; speedup 1.0000x reference)
//
#include <hip/hip_runtime.h>
#include <hip/hip_cooperative_groups.h>
#include <cstdint>
#include <cstddef>

namespace cg = cooperative_groups;

typedef unsigned short u16;
typedef __bf16 bf16x8 __attribute__((ext_vector_type(8)));
typedef float    f32x4 __attribute__((ext_vector_type(4)));
typedef unsigned int u32x4 __attribute__((ext_vector_type(4)));

// ---------- problem constants ----------
constexpr int BB   = 16;
constexpr int NN   = 2048;
constexpr int SS   = 512;
constexpr int DD   = 384;   // D1 = D2 = 384
constexpr int CIN  = 768;   // D1+D2
constexpr int HID  = 768;
constexpr int OUTC = 384;
constexpr int MROWS = BB * NN; // 32768
constexpr float KNN_EPS = 1.1920929e-07f; // finfo(f32).eps
constexpr float BN_EPS  = 1e-5f;

// ---------- workspace layout (bytes) ----------
constexpr size_t OFF_W0B  = 0;                              // 768*768 bf16
constexpr size_t OFF_W1B  = OFF_W0B  + (size_t)HID*CIN*2;   // 384*768 bf16
constexpr size_t OFF_IDX  = OFF_W1B  + (size_t)OUTC*HID*2;  // MROWS*5 int
constexpr size_t OFF_WGT  = OFF_IDX  + (size_t)MROWS*5*4;
constexpr size_t OFF_SUM1 = OFF_WGT  + (size_t)MROWS*5*4;   // 768*2 f32
constexpr size_t OFF_SUM2 = OFF_SUM1 + (size_t)HID*2*4;     // 384*2 f32
constexpr size_t OFF_COEF1= OFF_SUM2 + (size_t)OUTC*2*4;    // 768*2 f32
constexpr size_t OFF_COEF2= OFF_COEF1+ (size_t)HID*2*4;     // 384*2 f32
constexpr size_t OFF_XCAT = OFF_COEF2+ (size_t)OUTC*2*4;    // MROWS*768 bf16
constexpr size_t OFF_H1   = OFF_XCAT + (size_t)MROWS*CIN*2; // MROWS*768 bf16

// ---------- helpers ----------
__device__ inline float bf2f(u16 u){ unsigned int i = ((unsigned int)u)<<16; float f; __builtin_memcpy(&f,&i,4); return f; }
__device__ inline u16 f2bf(float f){ unsigned int x; __builtin_memcpy(&x,&f,4);
  unsigned int r = (x + 0x7fffu + ((x>>16)&1u)) >> 16; return (u16)r; }

__device__ inline void async16(const void* g, void* l){
  __builtin_amdgcn_global_load_lds((const __attribute__((address_space(1))) void*)g,
                                   (__attribute__((address_space(3))) void*)l, 16, 0, 0);
}

// ---------- W f32 -> bf16 ----------
__global__ void cvtw_kernel(const float* __restrict__ W0, const float* __restrict__ W1,
                            u16* __restrict__ W0b, u16* __restrict__ W1b){
  int t = blockIdx.x*256 + threadIdx.x;
  if (t < HID*CIN)  W0b[t] = f2bf(W0[t]);
  if (t < OUTC*HID) W1b[t] = f2bf(W1[t]);
}

// ---------- KNN: one wave per query ----------
__global__ __launch_bounds__(256) void knn_kernel(const float* __restrict__ xyz1,
                                                  const float* __restrict__ xyz2,
                                                  const int* __restrict__ elens,
                                                  int* __restrict__ idxO, float* __restrict__ wO){
  __shared__ f32x4 sp[SS];
  const int tid = threadIdx.x;
  const int wv = tid >> 6, lane = tid & 63;
  const int wg = blockIdx.x*4 + wv;       // global wave id = query id
  const int b = wg >> 11;                 // 2048 queries per batch
  const int n = wg & (NN-1);
  for (int s = tid; s < SS; s += 256){
    float x = xyz2[((size_t)b*SS + s)*3 + 0];
    float y = xyz2[((size_t)b*SS + s)*3 + 1];
    float z = xyz2[((size_t)b*SS + s)*3 + 2];
    f32x4 v; v[0]=x; v[1]=y; v[2]=z; v[3]=x*x+y*y+z*z;
    sp[s]=v;
  }
  __syncthreads();
  const size_t qoff = ((size_t)b*NN + n)*3;
  const float qx = xyz1[qoff+0], qy = xyz1[qoff+1], qz = xyz1[qoff+2];
  const float qq = qx*qx + qy*qy + qz*qz;
  const int Sl = elens[b];

  float d0=1e30f,d1=1e30f,d2v=1e30f,d3=1e30f,d4=1e30f;
  int   i0=0,i1=0,i2=0,i3=0,i4=0;
  #pragma unroll
  for (int j=0;j<8;j++){
    const int s = lane + j*64;
    f32x4 v = sp[s];
    float d = (s < Sl) ? (qq + v[3] - 2.f*(qx*v[0] + qy*v[1] + qz*v[2])) : 1e30f;
    bool lt4=d<d4, lt3=d<d3, lt2=d<d2v, lt1=d<d1, lt0=d<d0;
    float nd4 = lt3 ? d3 : (lt4 ? d : d4); int ni4 = lt3 ? i3 : (lt4 ? s : i4);
    float nd3 = lt2 ? d2v: (lt3 ? d : d3); int ni3 = lt2 ? i2 : (lt3 ? s : i3);
    float nd2 = lt1 ? d1 : (lt2 ? d : d2v);int ni2 = lt1 ? i1 : (lt2 ? s : i2);
    float nd1 = lt0 ? d0 : (lt1 ? d : d1); int ni1 = lt0 ? i0 : (lt1 ? s : i1);
    float nd0 = lt0 ? d  : d0;             int ni0 = lt0 ? s  : i0;
    d4=nd4;i4=ni4; d3=nd3;i3=ni3; d2v=nd2;i2=ni2; d1=nd1;i1=ni1; d0=nd0;i0=ni0;
  }
  float outd[5]; int outi[5];
  #pragma unroll
  for (int r=0;r<5;r++){
    float bd = d0; int bs = i0;
    #pragma unroll
    for (int m=1;m<64;m<<=1){
      float od = __shfl_xor(bd, m, 64);
      int   os = __shfl_xor(bs, m, 64);
      if (od < bd || (od == bd && os < bs)){ bd = od; bs = os; }
    }
    outd[r]=bd; outi[r]=bs;
    if (d0 == bd && i0 == bs){ d0=d1;i0=i1; d1=d2v;i1=i2; d2v=d3;i2=i3; d3=d4;i3=i4; d4=1e30f;i4=0; }
  }
  if (lane == 0){
    float r0=1.f/(outd[0]+KNN_EPS), r1=1.f/(outd[1]+KNN_EPS), r2=1.f/(outd[2]+KNN_EPS),
          r3=1.f/(outd[3]+KNN_EPS), r4=1.f/(outd[4]+KNN_EPS);
    float inv = 1.f/(r0+r1+r2+r3+r4);
    size_t base = (size_t)wg*5;
    idxO[base+0]=outi[0]; idxO[base+1]=outi[1]; idxO[base+2]=outi[2]; idxO[base+3]=outi[3]; idxO[base+4]=outi[4];
    wO[base+0]=r0*inv; wO[base+1]=r1*inv; wO[base+2]=r2*inv; wO[base+3]=r3*inv; wO[base+4]=r4*inv;
  }
}

// ---------- build xcat = [points1 | interp] in bf16 ----------
__global__ __launch_bounds__(384) void xcat_kernel(const float* __restrict__ p1,
                                                   const float* __restrict__ p2,
                                                   const int* __restrict__ idx,
                                                   const float* __restrict__ wgt,
                                                   u16* __restrict__ xcat){
  const int c = threadIdx.x;
  const int rowbase = blockIdx.x*8;
  for (int i=0;i<8;i++){
    const int row = rowbase + i;
    const int b = row >> 11;
    float v1 = p1[(size_t)row*DD + c];
    xcat[(size_t)row*CIN + c] = f2bf(v1);
    float acc = 0.f;
    size_t ib = (size_t)row*5;
    #pragma unroll
    for (int k=0;k<5;k++){
      int id = idx[ib+k]; float w = wgt[ib+k];
      acc += w * p2[((size_t)b*SS + id)*DD + c];
    }
    xcat[(size_t)row*CIN + DD + c] = f2bf(acc);
  }
}

// ---------- GEMM1 (phase-split, exact R6-measured 65us structure) ----------
__global__ __launch_bounds__(256, 4) void gemm1_kernel(const u16* __restrict__ A,
                                                       const u16* __restrict__ Bw,
                                                       u16* __restrict__ Cout,
                                                       const int* __restrict__ plen,
                                                       float* __restrict__ sums){
  constexpr int K   = CIN;
  constexpr int NC  = HID;
  constexpr int GX  = NC/128;      // 6
  constexpr int NT  = K/32;        // 24
  constexpr int NWG = GX*256;
  constexpr int CPX = NWG/8;
  __shared__ u16 Ash[2][128*32];
  __shared__ u16 Bsh[2][128*32];
  const int tid  = threadIdx.x;
  const int lane = tid & 63, wv = tid >> 6;
  const int wr = wv >> 1, wc = wv & 1;
  const int l15 = lane & 15, l16 = lane >> 4;
  const int swz = (l15 >> 1) & 3;

  const int logical = (blockIdx.x & 7)*CPX + (blockIdx.x >> 3);
  const int bn = logical % GX, bm = logical / GX;

  const int srow = tid >> 2;
  const int sk4  = (tid & 3) ^ ((tid >> 3) & 3);
  const u16* gA = A  + (size_t)(bm*128 + srow)*K + sk4*8;
  const u16* gB = Bw + (size_t)(bn*128 + srow)*K + sk4*8;
  const int dst0 = (wv*64)*16;
  const int dst1 = (256 + wv*64)*16;

  auto stageA = [&](int tt, int bi){
    async16(gA + tt*32,        (char*)&Ash[bi][0] + dst0);
    async16(gA + tt*32 + 64*K, (char*)&Ash[bi][0] + dst1);
  };
  auto stageB = [&](int tt, int bi){
    async16(gB + tt*32,        (char*)&Bsh[bi][0] + dst0);
    async16(gB + tt*32 + 64*K, (char*)&Bsh[bi][0] + dst1);
  };

  int aoff[4], boff[4];
  #pragma unroll
  for (int m=0;m<4;m++) aoff[m] = (wr*64 + m*16 + l15)*32 + ((l16 ^ swz) << 3);
  #pragma unroll
  for (int n=0;n<4;n++) boff[n] = (wc*64 + n*16 + l15)*32 + ((l16 ^ swz) << 3);

  f32x4 acc[4][4] = {};

  stageA(0,0); stageB(0,0); stageA(1,1); stageB(1,1);
  asm volatile("s_waitcnt vmcnt(4)" ::: "memory");
  __builtin_amdgcn_s_barrier();
  __builtin_amdgcn_sched_barrier(0);

  for (int t=0; t<NT; ++t){
    const int cur = t & 1;
    const int tt = (t+2 < NT) ? (t+2) : (NT-1);
    bf16x8 af0 = *reinterpret_cast<const bf16x8*>(&Ash[cur][aoff[0]]);
    bf16x8 af1 = *reinterpret_cast<const bf16x8*>(&Ash[cur][aoff[1]]);
    bf16x8 af2 = *reinterpret_cast<const bf16x8*>(&Ash[cur][aoff[2]]);
    bf16x8 af3 = *reinterpret_cast<const bf16x8*>(&Ash[cur][aoff[3]]);
    bf16x8 bv0 = *reinterpret_cast<const bf16x8*>(&Bsh[cur][boff[0]]);
    bf16x8 bv1 = *reinterpret_cast<const bf16x8*>(&Bsh[cur][boff[1]]);
    asm volatile("s_waitcnt lgkmcnt(0)" ::: "memory");
    __builtin_amdgcn_s_barrier();
    __builtin_amdgcn_sched_barrier(0);
    stageA(tt, cur);
    __builtin_amdgcn_s_setprio(1);
    acc[0][0] = __builtin_amdgcn_mfma_f32_16x16x32_bf16(af0, bv0, acc[0][0], 0,0,0);
    acc[1][0] = __builtin_amdgcn_mfma_f32_16x16x32_bf16(af1, bv0, acc[1][0], 0,0,0);
    acc[2][0] = __builtin_amdgcn_mfma_f32_16x16x32_bf16(af2, bv0, acc[2][0], 0,0,0);
    acc[3][0] = __builtin_amdgcn_mfma_f32_16x16x32_bf16(af3, bv0, acc[3][0], 0,0,0);
    acc[0][1] = __builtin_amdgcn_mfma_f32_16x16x32_bf16(af0, bv1, acc[0][1], 0,0,0);
    acc[1][1] = __builtin_amdgcn_mfma_f32_16x16x32_bf16(af1, bv1, acc[1][1], 0,0,0);
    acc[2][1] = __builtin_amdgcn_mfma_f32_16x16x32_bf16(af2, bv1, acc[2][1], 0,0,0);
    acc[3][1] = __builtin_amdgcn_mfma_f32_16x16x32_bf16(af3, bv1, acc[3][1], 0,0,0);
    __builtin_amdgcn_s_setprio(0);
    bf16x8 bv2 = *reinterpret_cast<const bf16x8*>(&Bsh[cur][boff[2]]);
    bf16x8 bv3 = *reinterpret_cast<const bf16x8*>(&Bsh[cur][boff[3]]);
    asm volatile("s_waitcnt lgkmcnt(0)" ::: "memory");
    __builtin_amdgcn_s_barrier();
    __builtin_amdgcn_sched_barrier(0);
    stageB(tt, cur);
    __builtin_amdgcn_s_setprio(1);
    acc[0][2] = __builtin_amdgcn_mfma_f32_16x16x32_bf16(af0, bv2, acc[0][2], 0,0,0);
    acc[1][2] = __builtin_amdgcn_mfma_f32_16x16x32_bf16(af1, bv2, acc[1][2], 0,0,0);
    acc[2][2] = __builtin_amdgcn_mfma_f32_16x16x32_bf16(af2, bv2, acc[2][2], 0,0,0);
    acc[3][2] = __builtin_amdgcn_mfma_f32_16x16x32_bf16(af3, bv2, acc[3][2], 0,0,0);
    acc[0][3] = __builtin_amdgcn_mfma_f32_16x16x32_bf16(af0, bv3, acc[0][3], 0,0,0);
    acc[1][3] = __builtin_amdgcn_mfma_f32_16x16x32_bf16(af1, bv3, acc[1][3], 0,0,0);
    acc[2][3] = __builtin_amdgcn_mfma_f32_16x16x32_bf16(af2, bv3, acc[2][3], 0,0,0);
    acc[3][3] = __builtin_amdgcn_mfma_f32_16x16x32_bf16(af3, bv3, acc[3][3], 0,0,0);
    __builtin_amdgcn_s_setprio(0);
    asm volatile("s_waitcnt vmcnt(4)" ::: "memory");
    __builtin_amdgcn_s_barrier();
    __builtin_amdgcn_sched_barrier(0);
  }
  asm volatile("s_waitcnt vmcnt(0)" ::: "memory");
  __syncthreads();

  #pragma unroll
  for (int m=0;m<4;m++){
    int r0 = bm*128 + wr*64 + m*16 + l16*4;
    #pragma unroll
    for (int n=0;n<4;n++){
      int c = bn*128 + wc*64 + n*16 + l15;
      #pragma unroll
      for (int r=0;r<4;r++)
        Cout[(size_t)(r0+r)*NC + c] = f2bf(acc[m][n][r]);
    }
  }

  const int pl = plen[bm >> 4];
  const int rbase = (bm & 15)*128 + wr*64 + l16*4;
  float cs[4] = {0.f,0.f,0.f,0.f}, cs2[4] = {0.f,0.f,0.f,0.f};
  #pragma unroll
  for (int m=0;m<4;m++){
    #pragma unroll
    for (int r=0;r<4;r++){
      if (rbase + m*16 + r < pl){
        #pragma unroll
        for (int n=0;n<4;n++){
          float v = acc[m][n][r];
          cs[n] += v; cs2[n] += v*v;
        }
      }
    }
  }
  #pragma unroll
  for (int n=0;n<4;n++){
    cs[n]  += __shfl_xor(cs[n], 16, 64);  cs[n]  += __shfl_xor(cs[n], 32, 64);
    cs2[n] += __shfl_xor(cs2[n], 16, 64); cs2[n] += __shfl_xor(cs2[n], 32, 64);
  }
  float* lsum = (float*)&Ash[0][0];
  lsum[tid] = 0.f;
  __syncthreads();
  if (l16 == 0){
    #pragma unroll
    for (int n=0;n<4;n++){
      int col = wc*64 + n*16 + l15;
      atomicAdd(&lsum[col], cs[n]);
      atomicAdd(&lsum[128 + col], cs2[n]);
    }
  }
  __syncthreads();
  if (tid < 128)       atomicAdd(&sums[bn*128 + tid], lsum[tid]);
  else                 atomicAdd(&sums[NC + bn*128 + (tid-128)], lsum[tid]);
}

// ---------- coef: a = g*rsqrt(var+eps), c = b - mean*a ----------
__global__ void coef_kernel(const float* __restrict__ sums, const int* __restrict__ plen,
                            const float* __restrict__ g, const float* __restrict__ bta,
                            float* __restrict__ coef, int C){
  int c = threadIdx.x;
  if (c >= C) return;
  float cnt = 0.f;
  for (int b=0;b<BB;b++) cnt += (float)plen[b];
  float mean = sums[c] / cnt;
  float var  = sums[C + c] / cnt - mean*mean;
  var = fmaxf(var, 0.f);
  float a = g[c] * rsqrtf(var + BN_EPS);
  coef[c] = a;
  coef[C + c] = bta[c] - mean*a;
}

// ---------- GEMM2 fused body (R2-submission structure, verified at 66us) ----------
// COOP=true: no mid C-write; stats -> grid.sync -> coef2 in-block -> single BN2+ReLU write.
// COOP=false: f32 C write + stats (final_kernel applies BN2+ReLU afterwards).
template<bool COOP>
__device__ __forceinline__ void gemm2_body(const u16* __restrict__ A,
                                           const u16* __restrict__ Bw,
                                           float* __restrict__ Cout,
                                           const int* __restrict__ plen,
                                           float* __restrict__ sums,
                                           const float* __restrict__ cf,
                                           const float* __restrict__ gam,
                                           const float* __restrict__ bet){
  constexpr int GX = 3;
  constexpr int K  = HID;
  constexpr int NC = OUTC;
  constexpr int NSTEP = K/32;
  constexpr int NWG = GX*256;
  constexpr int CPX = NWG/8;
  __shared__ u16 As[2][128*32];
  __shared__ u16 Bs[2][128*32];
  const int tid  = threadIdx.x;
  const int lane = tid & 63, wv = tid >> 6;
  const int wr = wv >> 1, wc = wv & 1;
  const int l15 = lane & 15, l16 = lane >> 4;

  const int logical = (blockIdx.x & 7)*CPX + (blockIdx.x >> 3);
  const int bn = logical % GX, bm = logical / GX;

  int c8S[2];
  const u16* Ab[2]; const u16* Bb[2];
  #pragma unroll
  for (int j=0;j<2;j++){
    int ch = j*256 + wv*64 + lane;
    int rowS = ch >> 2; c8S[j] = ch & 3;
    Ab[j] = A  + (size_t)(bm*128 + rowS)*K + c8S[j]*8;
    Bb[j] = Bw + (size_t)(bn*128 + rowS)*K + c8S[j]*8;
  }

  auto stageB = [&](int nb, int kt){
    #pragma unroll
    for (int j=0;j<2;j++)
      async16(Bb[j] + kt*32, (char*)&Bs[nb][0] + (j*256 + wv*64)*16);
  };
  u32x4 hv[2];
  auto loadA = [&](int kt){
    #pragma unroll
    for (int j=0;j<2;j++)
      hv[j] = *reinterpret_cast<const u32x4*>(Ab[j] + kt*32);
  };
  auto bnwrite = [&](int nb, int kt){
    #pragma unroll
    for (int j=0;j<2;j++){
      const int k0 = kt*32 + c8S[j]*8;
      float av[8], bv[8];
      *reinterpret_cast<f32x4*>(av)   = *reinterpret_cast<const f32x4*>(cf + k0);
      *reinterpret_cast<f32x4*>(av+4) = *reinterpret_cast<const f32x4*>(cf + k0 + 4);
      *reinterpret_cast<f32x4*>(bv)   = *reinterpret_cast<const f32x4*>(cf + K + k0);
      *reinterpret_cast<f32x4*>(bv+4) = *reinterpret_cast<const f32x4*>(cf + K + k0 + 4);
      u32x4 v = hv[j]; u32x4 o;
      #pragma unroll
      for (int q=0;q<4;q++){
        float lo = bf2f((u16)(v[q] & 0xffffu));
        float hi = bf2f((u16)(v[q] >> 16));
        lo = fmaxf(lo*av[2*q]   + bv[2*q],   0.f);
        hi = fmaxf(hi*av[2*q+1] + bv[2*q+1], 0.f);
        o[q] = (unsigned int)f2bf(lo) | ((unsigned int)f2bf(hi) << 16);
      }
      *reinterpret_cast<u32x4*>((char*)&As[nb][0] + (j*256 + wv*64)*16 + lane*16) = o;
    }
  };

  f32x4 acc[4][4] = {};

  loadA(0);
  stageB(0, 0);
  bnwrite(0, 0);
  __syncthreads();

  int cur = 0;
  for (int kt=0; kt<NSTEP; ++kt){
    const bool pf = (kt+1 < NSTEP);
    if (pf){
      loadA(kt+1);
      stageB(cur^1, kt+1);
    }
    bf16x8 af[4], bfr[4];
    #pragma unroll
    for (int m=0;m<4;m++){
      int r = wr*64 + m*16 + l15;
      af[m] = *reinterpret_cast<const bf16x8*>(&As[cur][r*32 + l16*8]);
    }
    #pragma unroll
    for (int n=0;n<4;n++){
      int c = wc*64 + n*16 + l15;
      bfr[n] = *reinterpret_cast<const bf16x8*>(&Bs[cur][c*32 + l16*8]);
    }
    #pragma unroll
    for (int m=0;m<4;m++)
      #pragma unroll
      for (int n=0;n<4;n++)
        acc[m][n] = __builtin_amdgcn_mfma_f32_16x16x32_bf16(af[m], bfr[n], acc[m][n], 0, 0, 0);
    if (pf) bnwrite(cur^1, kt+1);
    __syncthreads();
    cur ^= 1;
  }

  if (!COOP){
    // f32 C write now; final_kernel applies BN2+ReLU later
    #pragma unroll
    for (int m=0;m<4;m++){
      int r0 = bm*128 + wr*64 + m*16 + l16*4;
      #pragma unroll
      for (int n=0;n<4;n++){
        int c = bn*128 + wc*64 + n*16 + l15;
        #pragma unroll
        for (int r=0;r<4;r++)
          Cout[(size_t)(r0+r)*NC + c] = acc[m][n][r];
      }
    }
  }

  // ---- masked stats ----
  const int pl = plen[bm >> 4];
  const int rbase = (bm & 15)*128 + wr*64 + l16*4;
  float cs[4] = {0.f,0.f,0.f,0.f}, cs2[4] = {0.f,0.f,0.f,0.f};
  #pragma unroll
  for (int m=0;m<4;m++){
    #pragma unroll
    for (int r=0;r<4;r++){
      if (rbase + m*16 + r < pl){
        #pragma unroll
        for (int n=0;n<4;n++){
          float v = acc[m][n][r];
          cs[n] += v; cs2[n] += v*v;
        }
      }
    }
  }
  #pragma unroll
  for (int n=0;n<4;n++){
    cs[n]  += __shfl_xor(cs[n], 16, 64);  cs[n]  += __shfl_xor(cs[n], 32, 64);
    cs2[n] += __shfl_xor(cs2[n], 16, 64); cs2[n] += __shfl_xor(cs2[n], 32, 64);
  }
  float* lsum = (float*)&As[0][0];
  lsum[tid] = 0.f;
  __syncthreads();
  if (l16 == 0){
    #pragma unroll
    for (int n=0;n<4;n++){
      int col = wc*64 + n*16 + l15;
      atomicAdd(&lsum[col], cs[n]);
      atomicAdd(&lsum[128 + col], cs2[n]);
    }
  }
  __syncthreads();
  if (tid < 128)       atomicAdd(&sums[bn*128 + tid], lsum[tid]);
  else                 atomicAdd(&sums[NC + bn*128 + (tid-128)], lsum[tid]);

  if (COOP){
    __threadfence();
    cg::this_grid().sync();
    // device-coherent readback of sums (G16: plain loads may hit stale per-XCD L2)
    float* s = (float*)&As[0][0];
    if (tid < 128)      s[tid]       = atomicAdd(&sums[bn*128 + tid], 0.f);
    else                s[tid]       = atomicAdd(&sums[NC + bn*128 + (tid-128)], 0.f);
    __syncthreads();
    float cnt = 0.f;
    #pragma unroll
    for (int b=0;b<BB;b++) cnt += (float)plen[b];
    const float icnt = 1.f / cnt;
    #pragma unroll
    for (int n=0;n<4;n++){
      const int cl = wc*64 + n*16 + l15;       // col within this block's 128
      const int col = bn*128 + cl;
      float mean = s[cl] * icnt;
      float var  = fmaxf(s[128+cl]*icnt - mean*mean, 0.f);
      float a = gam[col] * rsqrtf(var + BN_EPS);
      float c = bet[col] - mean*a;
      #pragma unroll
      for (int m=0;m<4;m++){
        int r0 = bm*128 + wr*64 + m*16 + l16*4;
        #pragma unroll
        for (int r=0;r<4;r++)
          Cout[(size_t)(r0+r)*NC + col] = fmaxf(acc[m][n][r]*a + c, 0.f);
      }
    }
  }
}

__global__ __launch_bounds__(256, 3) void gemm2c_kernel(const u16* __restrict__ A,
                                                        const u16* __restrict__ Bw,
                                                        float* __restrict__ Cout,
                                                        const int* __restrict__ plen,
                                                        float* __restrict__ sums,
                                                        const float* __restrict__ cf,
                                                        const float* __restrict__ gam,
                                                        const float* __restrict__ bet){
  gemm2_body<true>(A, Bw, Cout, plen, sums, cf, gam, bet);
}

__global__ __launch_bounds__(256) void gemm2f_kernel(const u16* __restrict__ A,
                                                     const u16* __restrict__ Bw,
                                                     float* __restrict__ Cout,
                                                     const int* __restrict__ plen,
                                                     float* __restrict__ sums,
                                                     const float* __restrict__ cf){
  gemm2_body<false>(A, Bw, Cout, plen, sums, cf, nullptr, nullptr);
}

// ---------- final in-place: y = relu(y*a + c) ----------
__global__ __launch_bounds__(256) void final_kernel(float* __restrict__ Y,
                                                    const float* __restrict__ coef){
  size_t t = (size_t)blockIdx.x*256 + threadIdx.x;
  size_t f = t*4;
  int c = (int)(f % (size_t)OUTC);
  f32x4 v = *reinterpret_cast<const f32x4*>(Y + f);
  #pragma unroll
  for (int j=0;j<4;j++)
    v[j] = fmaxf(v[j]*coef[c+j] + coef[OUTC+c+j], 0.f);
  *reinterpret_cast<f32x4*>(Y + f) = v;
}

extern "C" void kernel_launch(void* const* d_in, const int* in_sizes, int n_in,
                              void* d_out, int out_size, void* d_ws, size_t ws_size,
                              hipStream_t stream){
  (void)in_sizes; (void)n_in; (void)out_size; (void)ws_size;
  const float* xyz1 = (const float*)d_in[0];
  const float* xyz2 = (const float*)d_in[1];
  const float* p1   = (const float*)d_in[2];
  const float* p2   = (const float*)d_in[3];
  const int*   plen = (const int*)d_in[4];
  const int*   elen = (const int*)d_in[5];
  const float* W0   = (const float*)d_in[7];
  const float* g0   = (const float*)d_in[8];
  const float* b0   = (const float*)d_in[9];
  const float* W1   = (const float*)d_in[10];
  const float* g1   = (const float*)d_in[11];
  const float* b1   = (const float*)d_in[12];
  float* out = (float*)d_out;
  char*  ws  = (char*)d_ws;

  u16*   W0b  = (u16*)  (ws + OFF_W0B);
  u16*   W1b  = (u16*)  (ws + OFF_W1B);
  int*   idxb = (int*)  (ws + OFF_IDX);
  float* wgtb = (float*)(ws + OFF_WGT);
  float* sum1 = (float*)(ws + OFF_SUM1);
  float* sum2 = (float*)(ws + OFF_SUM2);
  float* coef1= (float*)(ws + OFF_COEF1);
  float* coef2= (float*)(ws + OFF_COEF2);
  u16*   xcat = (u16*)  (ws + OFF_XCAT);
  u16*   h1   = (u16*)  (ws + OFF_H1);

  // zero the stats accumulators (atomics accumulate each launch)
  hipMemsetAsync(ws + OFF_SUM1, 0, (size_t)(HID*2 + OUTC*2)*4, stream);

  cvtw_kernel<<<(HID*CIN + 255)/256, 256, 0, stream>>>(W0, W1, W0b, W1b);
  knn_kernel<<<MROWS/4, 256, 0, stream>>>(xyz1, xyz2, elen, idxb, wgtb);
  xcat_kernel<<<MROWS/8, 384, 0, stream>>>(p1, p2, idxb, wgtb, xcat);

  // GEMM1: h1 = xcat @ W0^T (bf16 out, stats fused)
  gemm1_kernel<<<6*256, 256, 0, stream>>>(xcat, W0b, h1, plen, sum1);
  coef_kernel<<<1, HID, 0, stream>>>(sum1, plen, g0, b0, coef1, HID);

  // GEMM2: cooperative (fused BN2 epilogue) with automatic fallback to plain path
  const u16* a = h1; const u16* bw = W1b;
  void* ka[8];
  ka[0] = (void*)&a;    ka[1] = (void*)&bw;    ka[2] = (void*)&out;  ka[3] = (void*)&plen;
  ka[4] = (void*)&sum2; ka[5] = (void*)&coef1; ka[6] = (void*)&g1;   ka[7] = (void*)&b1;
  hipError_t ce = hipLaunchCooperativeKernel((void*)gemm2c_kernel, dim3(768), dim3(256),
                                             ka, 0, stream);
  if (ce != hipSuccess){
    gemm2f_kernel<<<768, 256, 0, stream>>>(h1, W1b, out, plen, sum2, coef1);
    coef_kernel<<<1, OUTC, 0, stream>>>(sum2, plen, g1, b1, coef2, OUTC);
    final_kernel<<<(size_t)MROWS*OUTC/4/256, 256, 0, stream>>>(out, coef2);
  }
}

// Round 10
// 187.429 us; speedup vs baseline: 1.7307x; 1.7307x over previous
//
#include <hip/hip_runtime.h>
#include <cstdint>
#include <cstddef>

typedef unsigned short u16;
typedef __bf16 bf16x8 __attribute__((ext_vector_type(8)));
typedef float    f32x4 __attribute__((ext_vector_type(4)));
typedef unsigned int u32x4 __attribute__((ext_vector_type(4)));
typedef unsigned short u16x4 __attribute__((ext_vector_type(4)));

// ---------- problem constants ----------
constexpr int BB   = 16;
constexpr int NN   = 2048;
constexpr int SS   = 512;
constexpr int DD   = 384;   // D1 = D2 = 384
constexpr int CIN  = 768;   // D1+D2
constexpr int HID  = 768;
constexpr int OUTC = 384;
constexpr int MROWS = BB * NN; // 32768
constexpr float KNN_EPS = 1.1920929e-07f; // finfo(f32).eps
constexpr float BN_EPS  = 1e-5f;

// ---------- workspace layout (bytes) ----------
constexpr size_t OFF_W0B  = 0;                              // 768*768 bf16
constexpr size_t OFF_W1B  = OFF_W0B  + (size_t)HID*CIN*2;   // 384*768 bf16
constexpr size_t OFF_IDX  = OFF_W1B  + (size_t)OUTC*HID*2;  // MROWS*5 int
constexpr size_t OFF_WGT  = OFF_IDX  + (size_t)MROWS*5*4;
constexpr size_t OFF_SUM1 = OFF_WGT  + (size_t)MROWS*5*4;   // 768*2 f32
constexpr size_t OFF_SUM2 = OFF_SUM1 + (size_t)HID*2*4;     // 384*2 f32
constexpr size_t OFF_COEF1= OFF_SUM2 + (size_t)OUTC*2*4;    // 768*2 f32
constexpr size_t OFF_COEF2= OFF_COEF1+ (size_t)HID*2*4;     // 384*2 f32
constexpr size_t OFF_XCAT = OFF_COEF2+ (size_t)OUTC*2*4;    // MROWS*768 bf16
constexpr size_t OFF_H1   = OFF_XCAT + (size_t)MROWS*CIN*2; // MROWS*768 bf16

// ---------- helpers ----------
__device__ inline float bf2f(u16 u){ unsigned int i = ((unsigned int)u)<<16; float f; __builtin_memcpy(&f,&i,4); return f; }
__device__ inline u16 f2bf(float f){ unsigned int x; __builtin_memcpy(&x,&f,4);
  unsigned int r = (x + 0x7fffu + ((x>>16)&1u)) >> 16; return (u16)r; }

__device__ inline void async16(const void* g, void* l){
  __builtin_amdgcn_global_load_lds((const __attribute__((address_space(1))) void*)g,
                                   (__attribute__((address_space(3))) void*)l, 16, 0, 0);
}

// ---------- W f32 -> bf16 ----------
__global__ void cvtw_kernel(const float* __restrict__ W0, const float* __restrict__ W1,
                            u16* __restrict__ W0b, u16* __restrict__ W1b){
  int t = blockIdx.x*256 + threadIdx.x;
  if (t < HID*CIN)  W0b[t] = f2bf(W0[t]);
  if (t < OUTC*HID) W1b[t] = f2bf(W1[t]);
}

// ---------- KNN: one wave per query ----------
__global__ __launch_bounds__(256) void knn_kernel(const float* __restrict__ xyz1,
                                                  const float* __restrict__ xyz2,
                                                  const int* __restrict__ elens,
                                                  int* __restrict__ idxO, float* __restrict__ wO){
  __shared__ f32x4 sp[SS];
  const int tid = threadIdx.x;
  const int wv = tid >> 6, lane = tid & 63;
  const int wg = blockIdx.x*4 + wv;       // global wave id = query id
  const int b = wg >> 11;                 // 2048 queries per batch
  const int n = wg & (NN-1);
  for (int s = tid; s < SS; s += 256){
    float x = xyz2[((size_t)b*SS + s)*3 + 0];
    float y = xyz2[((size_t)b*SS + s)*3 + 1];
    float z = xyz2[((size_t)b*SS + s)*3 + 2];
    f32x4 v; v[0]=x; v[1]=y; v[2]=z; v[3]=x*x+y*y+z*z;
    sp[s]=v;
  }
  __syncthreads();
  const size_t qoff = ((size_t)b*NN + n)*3;
  const float qx = xyz1[qoff+0], qy = xyz1[qoff+1], qz = xyz1[qoff+2];
  const float qq = qx*qx + qy*qy + qz*qz;
  const int Sl = elens[b];

  float d0=1e30f,d1=1e30f,d2v=1e30f,d3=1e30f,d4=1e30f;
  int   i0=0,i1=0,i2=0,i3=0,i4=0;
  #pragma unroll
  for (int j=0;j<8;j++){
    const int s = lane + j*64;
    f32x4 v = sp[s];
    float d = (s < Sl) ? (qq + v[3] - 2.f*(qx*v[0] + qy*v[1] + qz*v[2])) : 1e30f;
    bool lt4=d<d4, lt3=d<d3, lt2=d<d2v, lt1=d<d1, lt0=d<d0;
    float nd4 = lt3 ? d3 : (lt4 ? d : d4); int ni4 = lt3 ? i3 : (lt4 ? s : i4);
    float nd3 = lt2 ? d2v: (lt3 ? d : d3); int ni3 = lt2 ? i2 : (lt3 ? s : i3);
    float nd2 = lt1 ? d1 : (lt2 ? d : d2v);int ni2 = lt1 ? i1 : (lt2 ? s : i2);
    float nd1 = lt0 ? d0 : (lt1 ? d : d1); int ni1 = lt0 ? i0 : (lt1 ? s : i1);
    float nd0 = lt0 ? d  : d0;             int ni0 = lt0 ? s  : i0;
    d4=nd4;i4=ni4; d3=nd3;i3=ni3; d2v=nd2;i2=ni2; d1=nd1;i1=ni1; d0=nd0;i0=ni0;
  }
  float outd[5]; int outi[5];
  #pragma unroll
  for (int r=0;r<5;r++){
    float bd = d0; int bs = i0;
    #pragma unroll
    for (int m=1;m<64;m<<=1){
      float od = __shfl_xor(bd, m, 64);
      int   os = __shfl_xor(bs, m, 64);
      if (od < bd || (od == bd && os < bs)){ bd = od; bs = os; }
    }
    outd[r]=bd; outi[r]=bs;
    if (d0 == bd && i0 == bs){ d0=d1;i0=i1; d1=d2v;i1=i2; d2v=d3;i2=i3; d3=d4;i3=i4; d4=1e30f;i4=0; }
  }
  if (lane == 0){
    float r0=1.f/(outd[0]+KNN_EPS), r1=1.f/(outd[1]+KNN_EPS), r2=1.f/(outd[2]+KNN_EPS),
          r3=1.f/(outd[3]+KNN_EPS), r4=1.f/(outd[4]+KNN_EPS);
    float inv = 1.f/(r0+r1+r2+r3+r4);
    size_t base = (size_t)wg*5;
    idxO[base+0]=outi[0]; idxO[base+1]=outi[1]; idxO[base+2]=outi[2]; idxO[base+3]=outi[3]; idxO[base+4]=outi[4];
    wO[base+0]=r0*inv; wO[base+1]=r1*inv; wO[base+2]=r2*inv; wO[base+3]=r3*inv; wO[base+4]=r4*inv;
  }
}

// ---------- xcat (vectorized): 4 rows/block, 96 threads/row, f32x4 in -> u16x4 out ----------
__global__ __launch_bounds__(384) void xcat_kernel(const float* __restrict__ p1,
                                                   const float* __restrict__ p2,
                                                   const int* __restrict__ idx,
                                                   const float* __restrict__ wgt,
                                                   u16* __restrict__ xcat){
  const int t = threadIdx.x;
  const int rloc = t / 96, c4 = t % 96;
  const int row = blockIdx.x*4 + rloc;
  const int b = row >> 11;
  const int c = c4*4;
  f32x4 v1 = *reinterpret_cast<const f32x4*>(p1 + (size_t)row*DD + c);
  size_t ib = (size_t)row*5;
  f32x4 acc = {0.f,0.f,0.f,0.f};
  #pragma unroll
  for (int k=0;k<5;k++){
    int id = idx[ib+k]; float w = wgt[ib+k];
    f32x4 g = *reinterpret_cast<const f32x4*>(p2 + ((size_t)b*SS + id)*DD + c);
    #pragma unroll
    for (int j=0;j<4;j++) acc[j] += w * g[j];
  }
  u16x4 o1, o2;
  #pragma unroll
  for (int j=0;j<4;j++){ o1[j] = f2bf(v1[j]); o2[j] = f2bf(acc[j]); }
  *reinterpret_cast<u16x4*>(xcat + (size_t)row*CIN + c)      = o1;
  *reinterpret_cast<u16x4*>(xcat + (size_t)row*CIN + DD + c) = o2;
}

// ---------- GEMM1: 128x128 tile, 512 threads / 8 waves, phase-split, dist-2 dbuf ----------
// Same verified cadence/swizzle as the 65us R6 kernel; per-wave output 64x32 so
// occupancy is wave-limited (~24 waves/CU) instead of ~10.
__global__ __launch_bounds__(512, 6) void gemm1_kernel(const u16* __restrict__ A,
                                                       const u16* __restrict__ Bw,
                                                       u16* __restrict__ Cout,
                                                       const int* __restrict__ plen,
                                                       float* __restrict__ sums){
  constexpr int K   = CIN;         // 768
  constexpr int NC  = HID;         // 768
  constexpr int GX  = NC/128;      // 6
  constexpr int NT  = K/32;        // 24
  constexpr int NWG = GX*256;      // 1536
  constexpr int CPX = NWG/8;
  __shared__ u16 Ash[2][128*32];
  __shared__ u16 Bsh[2][128*32];
  const int tid  = threadIdx.x;
  const int lane = tid & 63, wv = tid >> 6;    // 8 waves
  const int wr = wv >> 2, wc = wv & 3;         // 2 x 4 wave grid, per-wave 64x32
  const int l15 = lane & 15, l16 = lane >> 4;
  const int swz = (l15 >> 1) & 3;

  const int logical = (blockIdx.x & 7)*CPX + (blockIdx.x >> 3);
  const int bn = logical % GX, bm = logical / GX;

  // staging: 512 chunks(16B) per 128x32 tile; 1 A-chunk + 1 B-chunk per thread
  const int srow = tid >> 2;
  const int sk4  = (tid & 3) ^ ((tid >> 3) & 3);
  const u16* gA = A  + (size_t)(bm*128 + srow)*K + sk4*8;
  const u16* gB = Bw + (size_t)(bn*128 + srow)*K + sk4*8;
  const int dst = (wv*64)*16;       // wave-uniform LDS byte base (lane x 16B appended by HW)

  auto stageA = [&](int tt, int bi){ async16(gA + tt*32, (char*)&Ash[bi][0] + dst); };
  auto stageB = [&](int tt, int bi){ async16(gB + tt*32, (char*)&Bsh[bi][0] + dst); };

  int aoff[4], boff[2];
  #pragma unroll
  for (int m=0;m<4;m++) aoff[m] = (wr*64 + m*16 + l15)*32 + ((l16 ^ swz) << 3);
  #pragma unroll
  for (int n=0;n<2;n++) boff[n] = (wc*32 + n*16 + l15)*32 + ((l16 ^ swz) << 3);

  f32x4 acc[4][2] = {};

  stageA(0,0); stageB(0,0); stageA(1,1); stageB(1,1);
  asm volatile("s_waitcnt vmcnt(2)" ::: "memory");   // tile 0 landed
  __builtin_amdgcn_s_barrier();
  __builtin_amdgcn_sched_barrier(0);

  for (int t=0; t<NT; ++t){
    const int cur = t & 1;
    const int tt = (t+2 < NT) ? (t+2) : (NT-1);   // clamped (R6-verified safe)
    // ---- phase 0: A frags + B n=0 ----
    bf16x8 af0 = *reinterpret_cast<const bf16x8*>(&Ash[cur][aoff[0]]);
    bf16x8 af1 = *reinterpret_cast<const bf16x8*>(&Ash[cur][aoff[1]]);
    bf16x8 af2 = *reinterpret_cast<const bf16x8*>(&Ash[cur][aoff[2]]);
    bf16x8 af3 = *reinterpret_cast<const bf16x8*>(&Ash[cur][aoff[3]]);
    bf16x8 bv0 = *reinterpret_cast<const bf16x8*>(&Bsh[cur][boff[0]]);
    asm volatile("s_waitcnt lgkmcnt(0)" ::: "memory");
    __builtin_amdgcn_s_barrier();                 // all waves' A reads done
    __builtin_amdgcn_sched_barrier(0);
    stageA(tt, cur);                              // A-range of buf[cur] free
    __builtin_amdgcn_s_setprio(1);
    acc[0][0] = __builtin_amdgcn_mfma_f32_16x16x32_bf16(af0, bv0, acc[0][0], 0,0,0);
    acc[1][0] = __builtin_amdgcn_mfma_f32_16x16x32_bf16(af1, bv0, acc[1][0], 0,0,0);
    acc[2][0] = __builtin_amdgcn_mfma_f32_16x16x32_bf16(af2, bv0, acc[2][0], 0,0,0);
    acc[3][0] = __builtin_amdgcn_mfma_f32_16x16x32_bf16(af3, bv0, acc[3][0], 0,0,0);
    __builtin_amdgcn_s_setprio(0);
    // ---- phase 1: B n=1 ----
    bf16x8 bv1 = *reinterpret_cast<const bf16x8*>(&Bsh[cur][boff[1]]);
    asm volatile("s_waitcnt lgkmcnt(0)" ::: "memory");
    __builtin_amdgcn_s_barrier();                 // all B reads of tile t done
    __builtin_amdgcn_sched_barrier(0);
    stageB(tt, cur);                              // B-range of buf[cur] free
    __builtin_amdgcn_s_setprio(1);
    acc[0][1] = __builtin_amdgcn_mfma_f32_16x16x32_bf16(af0, bv1, acc[0][1], 0,0,0);
    acc[1][1] = __builtin_amdgcn_mfma_f32_16x16x32_bf16(af1, bv1, acc[1][1], 0,0,0);
    acc[2][1] = __builtin_amdgcn_mfma_f32_16x16x32_bf16(af2, bv1, acc[2][1], 0,0,0);
    acc[3][1] = __builtin_amdgcn_mfma_f32_16x16x32_bf16(af3, bv1, acc[3][1], 0,0,0);
    __builtin_amdgcn_s_setprio(0);
    asm volatile("s_waitcnt vmcnt(2)" ::: "memory");  // tile t+1 landed; t+2 in flight
    __builtin_amdgcn_s_barrier();
    __builtin_amdgcn_sched_barrier(0);
  }
  asm volatile("s_waitcnt vmcnt(0)" ::: "memory");
  __syncthreads();

  // ---- C write ----
  #pragma unroll
  for (int m=0;m<4;m++){
    int r0 = bm*128 + wr*64 + m*16 + l16*4;
    #pragma unroll
    for (int n=0;n<2;n++){
      int c = bn*128 + wc*32 + n*16 + l15;
      #pragma unroll
      for (int r=0;r<4;r++)
        Cout[(size_t)(r0+r)*NC + c] = f2bf(acc[m][n][r]);
    }
  }

  // ---- fused masked stats ----
  const int pl = plen[bm >> 4];
  const int rbase = (bm & 15)*128 + wr*64 + l16*4;
  float cs[2] = {0.f,0.f}, cs2[2] = {0.f,0.f};
  #pragma unroll
  for (int m=0;m<4;m++){
    #pragma unroll
    for (int r=0;r<4;r++){
      if (rbase + m*16 + r < pl){
        #pragma unroll
        for (int n=0;n<2;n++){
          float v = acc[m][n][r];
          cs[n] += v; cs2[n] += v*v;
        }
      }
    }
  }
  #pragma unroll
  for (int n=0;n<2;n++){
    cs[n]  += __shfl_xor(cs[n], 16, 64);  cs[n]  += __shfl_xor(cs[n], 32, 64);
    cs2[n] += __shfl_xor(cs2[n], 16, 64); cs2[n] += __shfl_xor(cs2[n], 32, 64);
  }
  float* lsum = (float*)&Ash[0][0];
  if (tid < 256) lsum[tid] = 0.f;
  __syncthreads();
  if (l16 == 0){
    #pragma unroll
    for (int n=0;n<2;n++){
      int col = wc*32 + n*16 + l15;
      atomicAdd(&lsum[col], cs[n]);
      atomicAdd(&lsum[128 + col], cs2[n]);
    }
  }
  __syncthreads();
  if (tid < 128)       atomicAdd(&sums[bn*128 + tid], lsum[tid]);
  else if (tid < 256)  atomicAdd(&sums[NC + bn*128 + (tid-128)], lsum[tid]);
}

// ---------- coef: a = g*rsqrt(var+eps), c = b - mean*a ----------
__global__ void coef_kernel(const float* __restrict__ sums, const int* __restrict__ plen,
                            const float* __restrict__ g, const float* __restrict__ bta,
                            float* __restrict__ coef, int C){
  int c = threadIdx.x;
  if (c >= C) return;
  float cnt = 0.f;
  for (int b=0;b<BB;b++) cnt += (float)plen[b];
  float mean = sums[c] / cnt;
  float var  = sums[C + c] / cnt - mean*mean;
  var = fmaxf(var, 0.f);
  float a = g[c] * rsqrtf(var + BN_EPS);
  coef[c] = a;
  coef[C + c] = bta[c] - mean*a;
}

// ---------- GEMM2 (R3-verified 65.8us): ring-buffered, BN1+ReLU fused on A ----------
__global__ __launch_bounds__(256) void gemm2_kernel(const u16* __restrict__ A,
                                                    const u16* __restrict__ Bw,
                                                    float* __restrict__ Cout,
                                                    const int* __restrict__ plen,
                                                    float* __restrict__ sums,
                                                    const float* __restrict__ cf){
  constexpr int GX = 3;
  constexpr int K  = HID;
  constexpr int NC = GX*128;       // 384
  constexpr int NSTEP = K/32;      // 24
  constexpr int NWG = GX*256;
  constexpr int CPX = NWG/8;
  __shared__ u16 As[2][128*32];
  __shared__ u16 Bs[3][128*32];
  const int tid  = threadIdx.x;
  const int lane = tid & 63, wv = tid >> 6;
  const int wr = wv >> 1, wc = wv & 1;
  const int l15 = lane & 15, l16 = lane >> 4;
  const int sw  = (l15 >> 1) & 3;

  const int logical = (blockIdx.x & 7)*CPX + (blockIdx.x >> 3);
  const int bn = logical % GX, bm = logical / GX;

  int c8S[2], ldso[2];
  const u16* Ab[2]; const u16* Bb[2];
  #pragma unroll
  for (int j=0;j<2;j++){
    int ch = j*256 + wv*64 + lane;
    int row = ch >> 2;
    int c8 = (ch & 3) ^ ((ch >> 3) & 3);
    c8S[j] = c8;
    ldso[j] = (j*256 + wv*64)*16;
    Ab[j] = A  + (size_t)(bm*128 + row)*K + c8*8;
    Bb[j] = Bw + (size_t)(bn*128 + row)*K + c8*8;
  }

  auto stageB = [&](int nb, int kt){
    #pragma unroll
    for (int j=0;j<2;j++) async16(Bb[j] + kt*32, (char*)&Bs[nb][0] + ldso[j]);
  };
  u32x4 hv0, hv1;
  auto loadA = [&](int kt){
    hv0 = *reinterpret_cast<const u32x4*>(Ab[0] + kt*32);
    hv1 = *reinterpret_cast<const u32x4*>(Ab[1] + kt*32);
  };
  auto bnwrite = [&](int nb, int kt){
    #pragma unroll
    for (int j=0;j<2;j++){
      const int k0 = kt*32 + c8S[j]*8;
      float av[8], bv[8];
      *reinterpret_cast<f32x4*>(av)   = *reinterpret_cast<const f32x4*>(cf + k0);
      *reinterpret_cast<f32x4*>(av+4) = *reinterpret_cast<const f32x4*>(cf + k0 + 4);
      *reinterpret_cast<f32x4*>(bv)   = *reinterpret_cast<const f32x4*>(cf + K + k0);
      *reinterpret_cast<f32x4*>(bv+4) = *reinterpret_cast<const f32x4*>(cf + K + k0 + 4);
      u32x4 v = j ? hv1 : hv0; u32x4 o;
      #pragma unroll
      for (int q=0;q<4;q++){
        float lo = bf2f((u16)(v[q] & 0xffffu));
        float hi = bf2f((u16)(v[q] >> 16));
        lo = fmaxf(lo*av[2*q]   + bv[2*q],   0.f);
        hi = fmaxf(hi*av[2*q+1] + bv[2*q+1], 0.f);
        o[q] = (unsigned int)f2bf(lo) | ((unsigned int)f2bf(hi) << 16);
      }
      *reinterpret_cast<u32x4*>((char*)&As[nb][0] + ldso[j] + lane*16) = o;
    }
  };

  f32x4 acc[4][4] = {};

  loadA(0);
  __builtin_amdgcn_sched_barrier(0);
  stageB(0, 0); stageB(1, 1);
  bnwrite(0, 0);
  asm volatile("s_waitcnt vmcnt(2) lgkmcnt(0)" ::: "memory");
  __builtin_amdgcn_s_barrier();

  int rb = 0, wb = 2;
  for (int kt=0; kt<NSTEP; ++kt){
    const bool pf1 = (kt+1 < NSTEP), pf2 = (kt+2 < NSTEP);
    if (pf1) loadA(kt+1);
    __builtin_amdgcn_sched_barrier(0);
    if (pf2) stageB(wb, kt+2);

    bf16x8 af[4], bfr[4];
    const int aslot = kt & 1;
    #pragma unroll
    for (int m=0;m<4;m++){
      int r = wr*64 + m*16 + l15;
      af[m] = *reinterpret_cast<const bf16x8*>(&As[aslot][r*32 + ((l16 ^ sw) << 3)]);
    }
    #pragma unroll
    for (int n=0;n<4;n++){
      int c = wc*64 + n*16 + l15;
      bfr[n] = *reinterpret_cast<const bf16x8*>(&Bs[rb][c*32 + ((l16 ^ sw) << 3)]);
    }
    #pragma unroll
    for (int m=0;m<4;m++)
      #pragma unroll
      for (int n=0;n<4;n++)
        acc[m][n] = __builtin_amdgcn_mfma_f32_16x16x32_bf16(af[m], bfr[n], acc[m][n], 0, 0, 0);

    if (pf1) bnwrite((kt+1)&1, kt+1);

    if (pf1){
      if (pf2) asm volatile("s_waitcnt vmcnt(2) lgkmcnt(0)" ::: "memory");
      else     asm volatile("s_waitcnt vmcnt(0) lgkmcnt(0)" ::: "memory");
      __builtin_amdgcn_s_barrier();
    }
    rb = (rb==2) ? 0 : rb+1;
    wb = (wb==2) ? 0 : wb+1;
  }

  #pragma unroll
  for (int m=0;m<4;m++){
    int r0 = bm*128 + wr*64 + m*16 + l16*4;
    #pragma unroll
    for (int n=0;n<4;n++){
      int c = bn*128 + wc*64 + n*16 + l15;
      #pragma unroll
      for (int r=0;r<4;r++)
        Cout[(size_t)(r0+r)*NC + c] = acc[m][n][r];
    }
  }

  const int pl = plen[bm >> 4];
  const int rbase = (bm & 15)*128 + wr*64 + l16*4;
  float cs[4] = {0.f,0.f,0.f,0.f}, cs2[4] = {0.f,0.f,0.f,0.f};
  #pragma unroll
  for (int m=0;m<4;m++){
    #pragma unroll
    for (int r=0;r<4;r++){
      if (rbase + m*16 + r < pl){
        #pragma unroll
        for (int n=0;n<4;n++){
          float v = acc[m][n][r];
          cs[n] += v; cs2[n] += v*v;
        }
      }
    }
  }
  #pragma unroll
  for (int n=0;n<4;n++){
    cs[n]  += __shfl_xor(cs[n], 16, 64);  cs[n]  += __shfl_xor(cs[n], 32, 64);
    cs2[n] += __shfl_xor(cs2[n], 16, 64); cs2[n] += __shfl_xor(cs2[n], 32, 64);
  }
  float* lsum = (float*)&As[0][0];
  lsum[tid] = 0.f;
  __syncthreads();
  if (l16 == 0){
    #pragma unroll
    for (int n=0;n<4;n++){
      int col = wc*64 + n*16 + l15;
      atomicAdd(&lsum[col], cs[n]);
      atomicAdd(&lsum[128 + col], cs2[n]);
    }
  }
  __syncthreads();
  if (tid < 128)       atomicAdd(&sums[bn*128 + tid], lsum[tid]);
  else                 atomicAdd(&sums[NC + bn*128 + (tid-128)], lsum[tid]);
}

// ---------- final in-place: y = relu(y*a + c) ----------
__global__ __launch_bounds__(256) void final_kernel(float* __restrict__ Y,
                                                    const float* __restrict__ coef){
  size_t t = (size_t)blockIdx.x*256 + threadIdx.x;
  size_t f = t*4;
  int c = (int)(f % (size_t)OUTC);
  f32x4 v = *reinterpret_cast<const f32x4*>(Y + f);
  #pragma unroll
  for (int j=0;j<4;j++)
    v[j] = fmaxf(v[j]*coef[c+j] + coef[OUTC+c+j], 0.f);
  *reinterpret_cast<f32x4*>(Y + f) = v;
}

extern "C" void kernel_launch(void* const* d_in, const int* in_sizes, int n_in,
                              void* d_out, int out_size, void* d_ws, size_t ws_size,
                              hipStream_t stream){
  (void)in_sizes; (void)n_in; (void)out_size; (void)ws_size;
  const float* xyz1 = (const float*)d_in[0];
  const float* xyz2 = (const float*)d_in[1];
  const float* p1   = (const float*)d_in[2];
  const float* p2   = (const float*)d_in[3];
  const int*   plen = (const int*)d_in[4];
  const int*   elen = (const int*)d_in[5];
  const float* W0   = (const float*)d_in[7];
  const float* g0   = (const float*)d_in[8];
  const float* b0   = (const float*)d_in[9];
  const float* W1   = (const float*)d_in[10];
  const float* g1   = (const float*)d_in[11];
  const float* b1   = (const float*)d_in[12];
  float* out = (float*)d_out;
  char*  ws  = (char*)d_ws;

  u16*   W0b  = (u16*)  (ws + OFF_W0B);
  u16*   W1b  = (u16*)  (ws + OFF_W1B);
  int*   idxb = (int*)  (ws + OFF_IDX);
  float* wgtb = (float*)(ws + OFF_WGT);
  float* sum1 = (float*)(ws + OFF_SUM1);
  float* sum2 = (float*)(ws + OFF_SUM2);
  float* coef1= (float*)(ws + OFF_COEF1);
  float* coef2= (float*)(ws + OFF_COEF2);
  u16*   xcat = (u16*)  (ws + OFF_XCAT);
  u16*   h1   = (u16*)  (ws + OFF_H1);

  // zero the stats accumulators (atomics accumulate each launch)
  hipMemsetAsync(ws + OFF_SUM1, 0, (size_t)(HID*2 + OUTC*2)*4, stream);

  cvtw_kernel<<<(HID*CIN + 255)/256, 256, 0, stream>>>(W0, W1, W0b, W1b);
  knn_kernel<<<MROWS/4, 256, 0, stream>>>(xyz1, xyz2, elen, idxb, wgtb);
  xcat_kernel<<<MROWS/4, 384, 0, stream>>>(p1, p2, idxb, wgtb, xcat);

  // GEMM1: h1 = xcat @ W0^T (bf16 out, stats fused) — 8-wave variant
  gemm1_kernel<<<6*256, 512, 0, stream>>>(xcat, W0b, h1, plen, sum1);
  coef_kernel<<<1, HID, 0, stream>>>(sum1, plen, g0, b0, coef1, HID);

  // GEMM2: out = relu(bn1(h1)) @ W1^T (BN1 fused on A; f32 out; stats fused)
  gemm2_kernel<<<3*256, 256, 0, stream>>>(h1, W1b, out, plen, sum2, coef1);
  coef_kernel<<<1, OUTC, 0, stream>>>(sum2, plen, g1, b1, coef2, OUTC);
  final_kernel<<<(size_t)MROWS*OUTC/4/256, 256, 0, stream>>>(out, coef2);
}